// Round 1
// baseline (119.265 us; speedup 1.0000x reference)
//
#include <hip/hip_runtime.h>

// Total-variation-like sum over interior 62x62 of each 64x64 image.
// Input: fai[4096][2][64][64] f32 -> treated as 8192 images of 64x64.
// Output: single f32 scalar sum.

__global__ __launch_bounds__(256) void tv_sum_kernel(const float* __restrict__ fai,
                                                     float* __restrict__ out) {
    __shared__ float tile[64 * 64];

    const int img = blockIdx.x;                 // 0..8191
    const float* src = fai + (size_t)img * 4096;
    const int tid = threadIdx.x;

    // Stage the full 64x64 image into LDS with float4 loads:
    // 4096 floats = 1024 float4; 256 threads x 4 iters. Fully coalesced.
    const float4* src4 = (const float4*)src;
    float4* tile4 = (float4*)tile;
#pragma unroll
    for (int i = 0; i < 4; ++i) {
        tile4[tid + i * 256] = src4[tid + i * 256];
    }
    __syncthreads();

    // Interior cells: r,c in [1,62]; 62*62 = 3844 cells.
    float acc = 0.0f;
    for (int idx = tid; idx < 62 * 62; idx += 256) {
        const int r = idx / 62 + 1;
        const int c = idx % 62 + 1;
        const float ce = tile[r * 64 + c];
        const float up = tile[(r - 1) * 64 + c];
        const float dn = tile[(r + 1) * 64 + c];
        const float lf = tile[r * 64 + c - 1];
        const float rt = tile[r * 64 + c + 1];
        acc += fabsf(ce - up) + fabsf(ce - dn) + fabsf(ce - lf) + fabsf(ce - rt);
    }

    // Wave(64)-level shuffle reduction.
#pragma unroll
    for (int off = 32; off > 0; off >>= 1) {
        acc += __shfl_down(acc, off, 64);
    }

    // Block reduction across the 4 waves.
    __shared__ float wsum[4];
    if ((tid & 63) == 0) wsum[tid >> 6] = acc;
    __syncthreads();
    if (tid == 0) {
        const float s = (wsum[0] + wsum[1]) + (wsum[2] + wsum[3]);
        atomicAdd(out, s);   // device-scope by default on CDNA
    }
}

extern "C" void kernel_launch(void* const* d_in, const int* in_sizes, int n_in,
                              void* d_out, int out_size, void* d_ws, size_t ws_size,
                              hipStream_t stream) {
    const float* fai = (const float*)d_in[0];
    float* out = (float*)d_out;

    // d_out is poisoned (0xAA) once and never re-poisoned between replays;
    // we accumulate with atomics, so zero it every call (capture-safe).
    hipMemsetAsync(out, 0, sizeof(float), stream);

    const int n_images = 4096 * 2;  // in_sizes[0] / 4096
    tv_sum_kernel<<<n_images, 256, 0, stream>>>(fai, out);
}

// Round 2
// 47.916 us; speedup vs baseline: 2.4890x; 2.4890x over previous
//
#include <hip/hip_runtime.h>

// TV-like sum over interior 62x62 of each 64x64 image, edge-pair formulation:
//   vertical pair (i,i+1), cols c in [1,62]: weight (i==0||i==62) ? 1 : 2
//   horizontal pair (c,c+1), rows r in [1,62]: weight (c==0||c==62) ? 1 : 2
// Each element read exactly once (plus 1 overlap row per 16-row group).
// 64 threads per image: lane-group l=0..15 owns cols 4l..4l+3, row-group g
// owns rows 16g..16g+15 (+1 overlap row for the vertical boundary pair).

__global__ __launch_bounds__(256) void tv_sum_kernel(const float* __restrict__ fai,
                                                     float* __restrict__ out) {
    const int t   = blockIdx.x * 256 + threadIdx.x;
    const int img = t >> 6;          // 0..8191
    const int w   = t & 63;
    const int l   = w & 15;          // column chunk: cols 4l..4l+3
    const int r0  = (w >> 4) * 16;   // row-group start: 0,16,32,48

    const float4* src4 = (const float4*)(fai + (size_t)img * 4096);

    // Per-lane column weights (compile-time-ish, branch-free after setup).
    const int c0 = 4 * l, c2 = c0 + 2, c3 = c0 + 3;
    const float vw0 = (c0 >= 1) ? 1.f : 0.f;          // c0==0 only l==0
    const float vw3 = (c3 <= 62) ? 1.f : 0.f;         // c3==63 only l==15
    const float hw0 = (c0 == 0) ? 1.f : 2.f;          // pair (c0,c0+1)
    const float hw2 = (c2 == 62) ? 1.f : 2.f;         // pair (c2,c2+1)
    const float hw3 = (c3 <= 62) ? 2.f : 0.f;         // pair (c3,c3+1): gone at l==15

    float acc = 0.f;
    float4 prev;
#pragma unroll
    for (int rr = 0; rr <= 16; ++rr) {
        int row = r0 + rr;
        if (row > 63) row = 63;                 // clamped duplicate load; weight 0
        const float4 cur = src4[row * 16 + l];  // 16B/lane, coalesced 256B/row-group

        if (rr > 0) {
            const int i = r0 + rr - 1;          // vertical pair (i, i+1)
            const float wv = (i == 0 || i == 62) ? 1.f : (i < 63 ? 2.f : 0.f);
            const float v = vw0 * fabsf(cur.x - prev.x) + fabsf(cur.y - prev.y)
                          + fabsf(cur.z - prev.z) + vw3 * fabsf(cur.w - prev.w);
            acc += wv * v;
        }
        if (rr < 16) {
            const int hr = r0 + rr;             // horizontal row
            const float hrow = (hr >= 1 && hr <= 62) ? 1.f : 0.f;
            const float nx = __shfl_down(cur.x, 1, 64);  // next lane's first col
            const float h = hw0 * fabsf(cur.x - cur.y) + 2.f * fabsf(cur.y - cur.z)
                          + hw2 * fabsf(cur.z - cur.w) + hw3 * fabsf(cur.w - nx);
            acc += hrow * h;
        }
        prev = cur;
    }

    // Wave(64) shuffle reduction.
#pragma unroll
    for (int off = 32; off > 0; off >>= 1) acc += __shfl_down(acc, off, 64);

    // Block reduction across 4 waves, one atomic per block.
    __shared__ float wsum[4];
    if ((threadIdx.x & 63) == 0) wsum[threadIdx.x >> 6] = acc;
    __syncthreads();
    if (threadIdx.x == 0) {
        atomicAdd(out, (wsum[0] + wsum[1]) + (wsum[2] + wsum[3]));
    }
}

extern "C" void kernel_launch(void* const* d_in, const int* in_sizes, int n_in,
                              void* d_out, int out_size, void* d_ws, size_t ws_size,
                              hipStream_t stream) {
    const float* fai = (const float*)d_in[0];
    float* out = (float*)d_out;

    // d_out is poisoned once and not re-poisoned between replays; we
    // accumulate with atomics, so zero it every call (capture-safe).
    hipMemsetAsync(out, 0, sizeof(float), stream);

    const int n_threads = 8192 * 64;            // 64 threads per image
    tv_sum_kernel<<<n_threads / 256, 256, 0, stream>>>(fai, out);
}

// Round 3
// 35.204 us; speedup vs baseline: 3.3878x; 1.3611x over previous
//
#include <hip/hip_runtime.h>

// TV-like sum over interior 62x62 of each 64x64 image, edge-pair formulation:
//   vertical pair (i,i+1), col c in [1,62]: weight (i==0||i==62) ? 1 : 2
//   horizontal pair (c,c+1), row r in [1,62]: weight (c==0||c==62) ? 1 : 2
// 64 threads per image: lane-group l=0..15 owns cols 4l..4l+3, row-group g
// owns rows 16g..16g+15 (+1 overlap row for the boundary vertical pair).
// Two-stage reduction (no atomics, no memset): stage1 -> d_ws partials,
// stage2 overwrites out[0].

__global__ __launch_bounds__(256) void tv_stage1(const float* __restrict__ fai,
                                                 float* __restrict__ partial) {
    const int t   = blockIdx.x * 256 + threadIdx.x;
    const int img = t >> 6;          // 0..8191
    const int w   = t & 63;
    const int l   = w & 15;          // column chunk: cols 4l..4l+3
    const int r0  = (w >> 4) * 16;   // row-group start: 0,16,32,48

    const float4* src4 = (const float4*)(fai + (size_t)img * 4096);

    // Hoist ALL loads first: 17 back-to-back global_load_dwordx4 in flight.
    float4 v[17];
#pragma unroll
    for (int rr = 0; rr <= 16; ++rr) {
        int row = r0 + rr;
        if (row > 63) row = 63;                 // clamped duplicate; weight 0
        v[rr] = src4[row * 16 + l];
    }

    const int c0 = 4 * l, c2 = c0 + 2, c3 = c0 + 3;
    const float vw0 = (c0 >= 1) ? 1.f : 0.f;    // col 0 excluded (l==0 only)
    const float vw3 = (c3 <= 62) ? 1.f : 0.f;   // col 63 excluded (l==15 only)
    const float hw0 = (c0 == 0) ? 1.f : 2.f;    // pair (c0,c0+1)
    const float hw2 = (c2 == 62) ? 1.f : 2.f;   // pair (c2,c2+1)
    const float hw3 = (c3 <= 62) ? 2.f : 0.f;   // pair (c3,c3+1): absent at l==15

    float acc = 0.f;
#pragma unroll
    for (int rr = 0; rr < 16; ++rr) {
        const float4 cur = v[rr];
        // Horizontal pairs on row r0+rr (rows 1..62 only).
        const int hr = r0 + rr;
        const float hrow = (hr >= 1 && hr <= 62) ? 1.f : 0.f;
        const float nx = __shfl_down(cur.x, 1, 64);      // next lane's col c3+1
        acc += hrow * (hw0 * fabsf(cur.x - cur.y) + 2.f * fabsf(cur.y - cur.z)
                     + hw2 * fabsf(cur.z - cur.w) + hw3 * fabsf(cur.w - nx));
        // Vertical pair (i, i+1), i = r0+rr in [r0, r0+15].
        const float4 nxt = v[rr + 1];
        const float wv = (hr == 0 || hr == 62) ? 1.f : (hr < 63 ? 2.f : 0.f);
        acc += wv * (vw0 * fabsf(cur.x - nxt.x) + fabsf(cur.y - nxt.y)
                   + fabsf(cur.z - nxt.z) + vw3 * fabsf(cur.w - nxt.w));
    }

    // Wave(64) shuffle reduction, then cross-wave via LDS.
#pragma unroll
    for (int off = 32; off > 0; off >>= 1) acc += __shfl_down(acc, off, 64);
    __shared__ float wsum[4];
    if ((threadIdx.x & 63) == 0) wsum[threadIdx.x >> 6] = acc;
    __syncthreads();
    if (threadIdx.x == 0)
        partial[blockIdx.x] = (wsum[0] + wsum[1]) + (wsum[2] + wsum[3]);
}

__global__ __launch_bounds__(256) void tv_stage2(const float* __restrict__ partial,
                                                 float* __restrict__ out, int n) {
    float acc = 0.f;
    for (int i = threadIdx.x; i < n; i += 256) acc += partial[i];
#pragma unroll
    for (int off = 32; off > 0; off >>= 1) acc += __shfl_down(acc, off, 64);
    __shared__ float wsum[4];
    if ((threadIdx.x & 63) == 0) wsum[threadIdx.x >> 6] = acc;
    __syncthreads();
    if (threadIdx.x == 0)
        out[0] = (wsum[0] + wsum[1]) + (wsum[2] + wsum[3]);  // pure overwrite
}

extern "C" void kernel_launch(void* const* d_in, const int* in_sizes, int n_in,
                              void* d_out, int out_size, void* d_ws, size_t ws_size,
                              hipStream_t stream) {
    const float* fai = (const float*)d_in[0];
    float* out = (float*)d_out;
    float* partial = (float*)d_ws;              // 2048 floats, fully overwritten

    const int n_blocks = (8192 * 64) / 256;     // 2048
    tv_stage1<<<n_blocks, 256, 0, stream>>>(fai, partial);
    tv_stage2<<<1, 256, 0, stream>>>(partial, out, n_blocks);
}

// Round 4
// 30.493 us; speedup vs baseline: 3.9112x; 1.1545x over previous
//
#include <hip/hip_runtime.h>

// TV-like sum over interior 62x62 of each 64x64 image, edge-pair formulation:
//   vertical pair (i,i+1), col c in [1,62]: weight (i==0||i==62) ? 1 : 2
//   horizontal pair (c,c+1), row r in [1,62]: weight (c==0||c==62) ? 1 : 2
// Every element loaded EXACTLY once (boundary row via intra-wave shuffle).
// 64 threads per image: lane-group l=0..15 owns cols 4l..4l+3, row-group
// g=w>>4 owns rows 16g..16g+15. 1024-thread blocks = 16 images/block;
// one atomicAdd per block (512 total). Graph = [memset 4B, kernel].

__global__ __launch_bounds__(1024) void tv_fused(const float* __restrict__ fai,
                                                 float* __restrict__ out) {
    const int tid = threadIdx.x;
    const int w   = tid & 63;
    const int img = blockIdx.x * 16 + (tid >> 6);
    const int l   = w & 15;          // column chunk: cols 4l..4l+3
    const int r0  = (w >> 4) * 16;   // row-group start: 0,16,32,48

    const float4* src4 = (const float4*)(fai + (size_t)img * 4096);

    // 16 back-to-back global_load_dwordx4 (one base + 256B imm offsets).
    float4 v[16];
#pragma unroll
    for (int rr = 0; rr < 16; ++rr) v[rr] = src4[(r0 + rr) * 16 + l];

    // Boundary row 16g+16 == next row-group's v[0] (lane w+16, same l).
    // For g==3 the shuffle is out-of-range -> returns own value (finite),
    // and the i==63 vertical weight is 0 anyway.
    float4 b;
    b.x = __shfl_down(v[0].x, 16, 64);
    b.y = __shfl_down(v[0].y, 16, 64);
    b.z = __shfl_down(v[0].z, 16, 64);
    b.w = __shfl_down(v[0].w, 16, 64);

    const int c0 = 4 * l, c2 = c0 + 2, c3 = c0 + 3;
    const float vw0 = (c0 >= 1) ? 1.f : 0.f;    // col 0 excluded (l==0)
    const float vw3 = (c3 <= 62) ? 1.f : 0.f;   // col 63 excluded (l==15)
    const float hw0 = (c0 == 0) ? 1.f : 2.f;    // pair (c0,c0+1)
    const float hw2 = (c2 == 62) ? 1.f : 2.f;   // pair (c2,c2+1)
    const float hw3 = (c3 <= 62) ? 2.f : 0.f;   // pair (c3,c3+1): gone at l==15

    float acc = 0.f;
#pragma unroll
    for (int rr = 0; rr < 16; ++rr) {
        const float4 cur = v[rr];
        // Horizontal pairs on row hr (interior rows only).
        const int hr = r0 + rr;
        const float hrow = (hr >= 1 && hr <= 62) ? 1.f : 0.f;
        const float nx = __shfl_down(cur.x, 1, 64);     // next lane's col c3+1
        acc += hrow * (hw0 * fabsf(cur.x - cur.y) + 2.f * fabsf(cur.y - cur.z)
                     + hw2 * fabsf(cur.z - cur.w) + hw3 * fabsf(cur.w - nx));
        // Vertical pair (hr, hr+1).
        const float4 nxt = (rr < 15) ? v[rr + 1] : b;
        const float wv = (hr == 0 || hr == 62) ? 1.f : (hr < 63 ? 2.f : 0.f);
        acc += wv * (vw0 * fabsf(cur.x - nxt.x) + fabsf(cur.y - nxt.y)
                   + fabsf(cur.z - nxt.z) + vw3 * fabsf(cur.w - nxt.w));
    }

    // Wave(64) shuffle reduction.
#pragma unroll
    for (int off = 32; off > 0; off >>= 1) acc += __shfl_down(acc, off, 64);

    // Cross-wave reduction (16 waves), one atomic per block.
    __shared__ float wsum[16];
    if (w == 0) wsum[tid >> 6] = acc;
    __syncthreads();
    if (tid == 0) {
        float s = 0.f;
#pragma unroll
        for (int i = 0; i < 16; ++i) s += wsum[i];
        atomicAdd(out, s);
    }
}

extern "C" void kernel_launch(void* const* d_in, const int* in_sizes, int n_in,
                              void* d_out, int out_size, void* d_ws, size_t ws_size,
                              hipStream_t stream) {
    const float* fai = (const float*)d_in[0];
    float* out = (float*)d_out;

    // d_out is poisoned once and not re-poisoned between replays; we
    // accumulate with atomics, so zero it every call (capture-safe).
    hipMemsetAsync(out, 0, sizeof(float), stream);

    const int n_blocks = 8192 / 16;             // 512 blocks x 16 images
    tv_fused<<<n_blocks, 1024, 0, stream>>>(fai, out);
}